// Round 25
// baseline (73.948 us; speedup 1.0000x reference)
//
#include <hip/hip_runtime.h>
#include <math.h>

#define MM 16
#define CC 345
#define MC (MM*CC)   // 5520
#define KTOP 4
// Guard threshold in tc-space (validated R15/R20: absmax unchanged, ~0.5% trigger).
#define GAP_THR 3e-7f
#define NT 256       // 4 waves/block; no big LDS -> 8 blocks/CU (thread-limited)

__device__ __forceinline__ float fexp(float x) { return __expf(x); }
__device__ __forceinline__ float flog(float x) { return __logf(x); }

// width-16 reductions over a 16-lane group
__device__ __forceinline__ float rmax16(float v) {
    #pragma unroll
    for (int off = 8; off; off >>= 1) v = fmaxf(v, __shfl_xor(v, off, 16));
    return v;
}
__device__ __forceinline__ float rmin16(float v) {
    #pragma unroll
    for (int off = 8; off; off >>= 1) v = fminf(v, __shfl_xor(v, off, 16));
    return v;
}
__device__ __forceinline__ float rsum16(float v) {
    #pragma unroll
    for (int off = 8; off; off >>= 1) v += __shfl_xor(v, off, 16);
    return v;
}

// One block per batch row b. 256 threads = 4 waves. 3 barriers (common path).
// No logits tile in LDS: phase 2 and phase 4 read global (L2-hot after first
// touch); all numerics bit-identical to the R24 champion.
__global__ __launch_bounds__(NT)
void ens_main(const float* __restrict__ y, const int* __restrict__ labels,
              float* __restrict__ out, float* __restrict__ partial, int B)
{
    const int b   = blockIdx.x;
    const int tid = threadIdx.x;

    __shared__ float s_truep[MM], s_epl[MM], s_mx[MM], s_tpp[MM];
    __shared__ float s_w[MM], s_pw[MM];
    __shared__ float s_red[NT/64];
    __shared__ float s_lab;           // ems_out[label]
    __shared__ int   s_need;
    __shared__ unsigned s_selmask;

    const int label = labels[b];
    const float* yb = y + (size_t)b * MC;

    // ---- Phase 2: per-m softmax stats, 16 lanes per m (R5-verified pattern),
    // register-cached from GLOBAL. Same values & order as R24 -> bit-exact.
    {
        const int m = tid >> 4;
        const int l = tid & 15;
        const float* row = yb + m * CC;
        float v[22];
        float mx = -INFINITY;
        #pragma unroll
        for (int k = 0; k < 22; ++k) {
            const int c = l + (k << 4);
            if (c < CC) { v[k] = row[c]; mx = fmaxf(mx, v[k]); }
            else          v[k] = 0.f;
        }
        mx = rmax16(mx);
        float se = 0.f;
        #pragma unroll
        for (int k = 0; k < 22; ++k) {
            const int c = l + (k << 4);
            if (c < CC) se += fexp(v[k] - mx);
        }
        se = rsum16(se);
        if (l == 0) {
            const float lt = row[label];
            s_mx[m]    = mx;                          // exact max, reused by 3b
            s_truep[m] = fexp(lt - mx) / se;          // fast probs[b,m,label]
            s_epl[m]   = -(lt - mx - flog(se));       // -log_softmax[b,m,label]
        }
    }
    __syncthreads();   // #1 — stats ready

    // ---- Phase 3a + speculative 3c (lanes 0..15, R24-verbatim): everything
    // except pw is sel-independent; pw published speculatively, corrected by
    // the rare guarded path.
    if (tid < MM) {
        const int l = tid;
        const size_t off_wm = (size_t)B * CC + 3;
        const size_t off_tc = off_wm + (size_t)B * MM;

        const float tp = s_truep[l];
        const float mx = rmax16(tp);
        const float e  = fexp(tp - mx);
        const float tc = e / rsum16(e);
        const float s1 = fmaxf(rsum16(fabsf(tc)), 1e-12f);
        const float wm = tc / s1;
        int rank = 0;
        #pragma unroll
        for (int j = 0; j < MM; ++j) {
            const float vj = __shfl(tc, j, 16);
            rank += (vj > tc) || (vj == tc && j < l);
        }
        const bool sel = (rank < KTOP);
        const float val4 = rmin16(sel ? tc : INFINITY);    // smallest selected
        const float val5 = rmax16(sel ? -INFINITY : tc);   // largest unselected
        if (l == 0) s_need = (val4 - val5 < GAP_THR) ? 1 : 0;

        // speculative pw from fast selection
        const float post = sel ? tc : 0.f;
        const float psum = fmaxf(rsum16(fabsf(post)), 1e-12f);
        s_pw[l] = post / psum;
        s_w[l]  = wm;

        // sel-independent finishers
        const float mw = rmax16(wm);
        const float ex = fexp(wm - mw);
        const float xv = ex / rsum16(ex);
        const float mt = rmax16(tc);
        const float et = fexp(tc - mt);
        const float tv = et / rsum16(et);
        const float childp = s_epl[l] * xv;
        const float confp  = fmaxf(xv, 0.f) - xv * tv + flog(1.f + fexp(-fabsf(xv)));
        const float childs = rsum16(childp);
        const float confs  = rsum16(confp);
        if (l == 0) {
            partial[(size_t)b * 3 + 0] = childs;
            partial[(size_t)b * 3 + 1] = confs;
        }
        out[off_wm + (size_t)b * MM + l] = xv;  // wm_soft
        out[off_tc + (size_t)b * MM + l] = tc;  // true_confs
    }
    __syncthreads();   // #2 — weights (speculative) + s_need ready

    // ---- Phase 3b (R24-verbatim internals, rare): BIT-EXACT round-1 chain;
    // corrects only s_pw. Block-uniform condition -> conditional barriers legal.
    if (s_need) {
        {
            const int m = tid >> 4;
            const int l = tid & 15;
            const float* row = yb + m * CC;
            const float mx = s_mx[m];
            float se = 0.f;
            for (int c = l; c < CC; c += 16) se += expf(row[c] - mx);
            se = rsum16(se);
            if (l == 0) s_tpp[m] = expf(row[label] - mx) / se;
        }
        __syncthreads();
        if (tid == 0) {
            float tcp[MM];
            float mxx = -INFINITY;
            for (int m = 0; m < MM; ++m) mxx = fmaxf(mxx, s_tpp[m]);
            float ses = 0.f;
            for (int m = 0; m < MM; ++m) { tcp[m] = expf(s_tpp[m] - mxx); ses += tcp[m]; }
            for (int m = 0; m < MM; ++m) tcp[m] /= ses;
            bool used[MM];
            for (int m = 0; m < MM; ++m) used[m] = false;
            unsigned msk = 0;
            for (int k = 0; k < KTOP; ++k) {
                int bi = -1; float bv = -INFINITY;
                for (int m = 0; m < MM; ++m)
                    if (!used[m] && tcp[m] > bv) { bv = tcp[m]; bi = m; }
                used[bi] = true; msk |= (1u << bi);
            }
            s_selmask = msk;
        }
        __syncthreads();
        if (tid < MM) {
            const int l = tid;
            // recompute tc exactly as in 3a (same inputs -> same bits)
            const float tp = s_truep[l];
            const float mx = rmax16(tp);
            const float e  = fexp(tp - mx);
            const float tc = e / rsum16(e);
            const bool sel2 = ((s_selmask >> l) & 1u) != 0;
            const float post = sel2 ? tc : 0.f;
            const float psum = fmaxf(rsum16(fabsf(post)), 1e-12f);
            s_pw[l] = post / psum;
        }
        __syncthreads();   // republish corrected pw
    }

    // ---- Phase 4+5 fused: two columns per thread (c, c+256) read from
    // GLOBAL (L2-hot rows, coalesced per m); ensemble loss via UNSHIFTED
    // log-sum-exp; only ems[label] kept (single s_lab float).
    {
        const int c0 = tid;            // always < 345
        const int c1 = tid + NT;
        const bool act1 = (c1 < CC);
        float a0 = 0.f, p0 = 0.f, a1 = 0.f, p1 = 0.f;
        #pragma unroll
        for (int m = 0; m < MM; ++m) {
            const float w_ = s_w[m];
            const float q_ = s_pw[m];
            const float v0 = yb[m * CC + c0];
            a0 = fmaf(v0, w_, a0);
            p0 = fmaf(v0, q_, p0);
            if (act1) {
                const float v1 = yb[m * CC + c1];
                a1 = fmaf(v1, w_, a1);
                p1 = fmaf(v1, q_, p1);
            }
        }
        if (c0 == label) s_lab = a0;
        if (act1 && c1 == label) s_lab = a1;
        out[(size_t)b * CC + c0] = p0;             // ems_out_post
        if (act1) out[(size_t)b * CC + c1] = p1;

        float e = fexp(a0) + (act1 ? fexp(a1) : 0.f);
        #pragma unroll
        for (int off = 32; off; off >>= 1) e += __shfl_xor(e, off);
        if ((tid & 63) == 0) s_red[tid >> 6] = e;
        __syncthreads();   // #3 — covers s_lab + s_red
        if (tid == 0) {
            float s = 0.f;
            #pragma unroll
            for (int w = 0; w < NT/64; ++w) s += s_red[w];
            partial[(size_t)b * 3 + 2] = -(s_lab - flog(s));
        }
    }
}

// Two-stage deterministic reduction of per-b partials -> the 3 scalar losses.
__global__ __launch_bounds__(64)
void ens_reduce1(const float* __restrict__ partial, double* __restrict__ ws2, int B)
{
    const int t  = threadIdx.x;     // 0..63
    const int i  = blockIdx.x;      // 0..63
    const int r0 = i * 128 + t * 2; // 128 rows per block
    double c = 0.0, f = 0.0, e = 0.0;
    #pragma unroll
    for (int k = 0; k < 2; ++k) {
        const int r = r0 + k;
        c += (double)partial[(size_t)r * 3 + 0];
        f += (double)partial[(size_t)r * 3 + 1];
        e += (double)partial[(size_t)r * 3 + 2];
    }
    #pragma unroll
    for (int off = 32; off; off >>= 1) {
        c += __shfl_xor(c, off);
        f += __shfl_xor(f, off);
        e += __shfl_xor(e, off);
    }
    if (t == 0) {
        ws2[(size_t)i * 3 + 0] = c;
        ws2[(size_t)i * 3 + 1] = f;
        ws2[(size_t)i * 3 + 2] = e;
    }
}

__global__ __launch_bounds__(64)
void ens_reduce2(const double* __restrict__ ws2, float* __restrict__ out, int B)
{
    const int t = threadIdx.x;
    double c = ws2[(size_t)t * 3 + 0];
    double f = ws2[(size_t)t * 3 + 1];
    double e = ws2[(size_t)t * 3 + 2];
    #pragma unroll
    for (int off = 32; off; off >>= 1) {
        c += __shfl_xor(c, off);
        f += __shfl_xor(f, off);
        e += __shfl_xor(e, off);
    }
    if (t == 0) {
        const size_t base = (size_t)B * CC;
        out[base + 0] = (float)(c / (double)((size_t)B * MM));  // child_loss
        out[base + 1] = (float)(f / (double)((size_t)B * MM));  // confidence_loss
        out[base + 2] = (float)(e / (double)B);                 // ensemble_loss
    }
}

extern "C" void kernel_launch(void* const* d_in, const int* in_sizes, int n_in,
                              void* d_out, int out_size, void* d_ws, size_t ws_size,
                              hipStream_t stream)
{
    const float* y      = (const float*)d_in[0];
    const int*   labels = (const int*)d_in[1];
    const int    B      = in_sizes[1];      // 8192
    float* out     = (float*)d_out;
    float* partial = (float*)d_ws;          // B*3 floats
    double* ws2    = (double*)((char*)d_ws + (((size_t)B * 3 * sizeof(float) + 255) & ~(size_t)255));

    ens_main<<<dim3(B), dim3(NT), 0, stream>>>(y, labels, out, partial, B);
    ens_reduce1<<<dim3(64), dim3(64), 0, stream>>>(partial, ws2, B);
    ens_reduce2<<<dim3(1), dim3(64), 0, stream>>>(ws2, out, B);
}

// Round 26
// 62.011 us; speedup vs baseline: 1.1925x; 1.1925x over previous
//
#include <hip/hip_runtime.h>
#include <math.h>

#define MM 16
#define CC 345
#define MC (MM*CC)   // 5520
#define KTOP 4
// Guard threshold in tc-space (validated R15/R20: absmax unchanged, ~0.5% trigger).
#define GAP_THR 3e-7f
#define NT 256       // 4 waves/block; ~22.3 KB LDS -> 7 blocks/CU

__device__ __forceinline__ float fexp(float x) { return __expf(x); }
__device__ __forceinline__ float flog(float x) { return __logf(x); }

// width-16 reductions over a 16-lane group
__device__ __forceinline__ float rmax16(float v) {
    #pragma unroll
    for (int off = 8; off; off >>= 1) v = fmaxf(v, __shfl_xor(v, off, 16));
    return v;
}
__device__ __forceinline__ float rmin16(float v) {
    #pragma unroll
    for (int off = 8; off; off >>= 1) v = fminf(v, __shfl_xor(v, off, 16));
    return v;
}
__device__ __forceinline__ float rsum16(float v) {
    #pragma unroll
    for (int off = 8; off; off >>= 1) v += __shfl_xor(v, off, 16);
    return v;
}

// One block per batch row b. 256 threads = 4 waves. 3 barriers (common path).
// Staging (global->LDS) and phase-2 stats (global->regs) are issued with NO
// barrier between them: independent loads overlap, phase-2 hits L1 on the
// just-fetched lines. Barrier #1 covers both.
__global__ __launch_bounds__(NT)
void ens_main(const float* __restrict__ y, const int* __restrict__ labels,
              float* __restrict__ out, float* __restrict__ partial, int B)
{
    const int b   = blockIdx.x;
    const int tid = threadIdx.x;

    __shared__ float sl[MC + 64];     // logits tile (+pad) ~22.3 KB
    __shared__ float s_truep[MM], s_epl[MM], s_mx[MM], s_tpp[MM];
    __shared__ float s_w[MM], s_pw[MM];
    __shared__ float s_red[NT/64];
    __shared__ float s_lab;           // ems_out[label]
    __shared__ int   s_need;
    __shared__ unsigned s_selmask;

    const int label = labels[b];
    const float* yb = y + (size_t)b * MC;

    // ---- Phase 1 (issue only): global -> LDS, vectorized float4
    {
        const float4* src = reinterpret_cast<const float4*>(yb);
        float4* dst = reinterpret_cast<float4*>(sl);
        for (int i = tid; i < MC/4; i += NT) dst[i] = src[i];
    }
    // NO barrier here — phase 2 reads the same data from GLOBAL (L1-hot).

    // ---- Phase 2: per-m softmax stats, 16 lanes per m (R5/R25-verified
    // pattern), register-cached from GLOBAL. Bit-exact vs R24.
    {
        const int m = tid >> 4;
        const int l = tid & 15;
        const float* row = yb + m * CC;
        float v[22];
        float mx = -INFINITY;
        #pragma unroll
        for (int k = 0; k < 22; ++k) {
            const int c = l + (k << 4);
            if (c < CC) { v[k] = row[c]; mx = fmaxf(mx, v[k]); }
            else          v[k] = 0.f;
        }
        mx = rmax16(mx);
        float se = 0.f;
        #pragma unroll
        for (int k = 0; k < 22; ++k) {
            const int c = l + (k << 4);
            if (c < CC) se += fexp(v[k] - mx);
        }
        se = rsum16(se);
        if (l == 0) {
            const float lt = row[label];
            s_mx[m]    = mx;                          // exact max, reused by 3b
            s_truep[m] = fexp(lt - mx) / se;          // fast probs[b,m,label]
            s_epl[m]   = -(lt - mx - flog(se));       // -log_softmax[b,m,label]
        }
    }
    __syncthreads();   // #1 — covers staging writes AND stats

    // ---- Phase 3a + speculative 3c (lanes 0..15, R24-verbatim): everything
    // except pw is sel-independent; pw published speculatively, corrected by
    // the rare guarded path.
    if (tid < MM) {
        const int l = tid;
        const size_t off_wm = (size_t)B * CC + 3;
        const size_t off_tc = off_wm + (size_t)B * MM;

        const float tp = s_truep[l];
        const float mx = rmax16(tp);
        const float e  = fexp(tp - mx);
        const float tc = e / rsum16(e);
        const float s1 = fmaxf(rsum16(fabsf(tc)), 1e-12f);
        const float wm = tc / s1;
        int rank = 0;
        #pragma unroll
        for (int j = 0; j < MM; ++j) {
            const float vj = __shfl(tc, j, 16);
            rank += (vj > tc) || (vj == tc && j < l);
        }
        const bool sel = (rank < KTOP);
        const float val4 = rmin16(sel ? tc : INFINITY);    // smallest selected
        const float val5 = rmax16(sel ? -INFINITY : tc);   // largest unselected
        if (l == 0) s_need = (val4 - val5 < GAP_THR) ? 1 : 0;

        // speculative pw from fast selection
        const float post = sel ? tc : 0.f;
        const float psum = fmaxf(rsum16(fabsf(post)), 1e-12f);
        s_pw[l] = post / psum;
        s_w[l]  = wm;

        // sel-independent finishers
        const float mw = rmax16(wm);
        const float ex = fexp(wm - mw);
        const float xv = ex / rsum16(ex);
        const float mt = rmax16(tc);
        const float et = fexp(tc - mt);
        const float tv = et / rsum16(et);
        const float childp = s_epl[l] * xv;
        const float confp  = fmaxf(xv, 0.f) - xv * tv + flog(1.f + fexp(-fabsf(xv)));
        const float childs = rsum16(childp);
        const float confs  = rsum16(confp);
        if (l == 0) {
            partial[(size_t)b * 3 + 0] = childs;
            partial[(size_t)b * 3 + 1] = confs;
        }
        out[off_wm + (size_t)b * MM + l] = xv;  // wm_soft
        out[off_tc + (size_t)b * MM + l] = tc;  // true_confs
    }
    __syncthreads();   // #2 — weights (speculative) + s_need ready

    // ---- Phase 3b (R24-verbatim internals, rare): BIT-EXACT round-1 chain;
    // corrects only s_pw. Block-uniform condition -> conditional barriers legal.
    if (s_need) {
        {
            const int m = tid >> 4;
            const int l = tid & 15;
            const float* row = sl + m * CC;
            const float mx = s_mx[m];
            float se = 0.f;
            for (int c = l; c < CC; c += 16) se += expf(row[c] - mx);
            se = rsum16(se);
            if (l == 0) s_tpp[m] = expf(row[label] - mx) / se;
        }
        __syncthreads();
        if (tid == 0) {
            float tcp[MM];
            float mxx = -INFINITY;
            for (int m = 0; m < MM; ++m) mxx = fmaxf(mxx, s_tpp[m]);
            float ses = 0.f;
            for (int m = 0; m < MM; ++m) { tcp[m] = expf(s_tpp[m] - mxx); ses += tcp[m]; }
            for (int m = 0; m < MM; ++m) tcp[m] /= ses;
            bool used[MM];
            for (int m = 0; m < MM; ++m) used[m] = false;
            unsigned msk = 0;
            for (int k = 0; k < KTOP; ++k) {
                int bi = -1; float bv = -INFINITY;
                for (int m = 0; m < MM; ++m)
                    if (!used[m] && tcp[m] > bv) { bv = tcp[m]; bi = m; }
                used[bi] = true; msk |= (1u << bi);
            }
            s_selmask = msk;
        }
        __syncthreads();
        if (tid < MM) {
            const int l = tid;
            // recompute tc exactly as in 3a (same inputs -> same bits)
            const float tp = s_truep[l];
            const float mx = rmax16(tp);
            const float e  = fexp(tp - mx);
            const float tc = e / rsum16(e);
            const bool sel2 = ((s_selmask >> l) & 1u) != 0;
            const float post = sel2 ? tc : 0.f;
            const float psum = fmaxf(rsum16(fabsf(post)), 1e-12f);
            s_pw[l] = post / psum;
        }
        __syncthreads();   // republish corrected pw
    }

    // ---- Phase 4+5 fused (R24-verbatim): two columns per thread (c, c+256)
    // from the LDS tile; ensemble loss via UNSHIFTED log-sum-exp; only
    // ems[label] kept (single s_lab float).
    {
        const int c0 = tid;            // always < 345
        const int c1 = tid + NT;
        const bool act1 = (c1 < CC);
        float a0 = 0.f, p0 = 0.f, a1 = 0.f, p1 = 0.f;
        #pragma unroll
        for (int m = 0; m < MM; ++m) {
            const float w_ = s_w[m];
            const float q_ = s_pw[m];
            const float v0 = sl[m * CC + c0];
            a0 = fmaf(v0, w_, a0);
            p0 = fmaf(v0, q_, p0);
            if (act1) {
                const float v1 = sl[m * CC + c1];
                a1 = fmaf(v1, w_, a1);
                p1 = fmaf(v1, q_, p1);
            }
        }
        if (c0 == label) s_lab = a0;
        if (act1 && c1 == label) s_lab = a1;
        out[(size_t)b * CC + c0] = p0;             // ems_out_post
        if (act1) out[(size_t)b * CC + c1] = p1;

        float e = fexp(a0) + (act1 ? fexp(a1) : 0.f);
        #pragma unroll
        for (int off = 32; off; off >>= 1) e += __shfl_xor(e, off);
        if ((tid & 63) == 0) s_red[tid >> 6] = e;
        __syncthreads();   // #3 — covers s_lab + s_red
        if (tid == 0) {
            float s = 0.f;
            #pragma unroll
            for (int w = 0; w < NT/64; ++w) s += s_red[w];
            partial[(size_t)b * 3 + 2] = -(s_lab - flog(s));
        }
    }
}

// Two-stage deterministic reduction of per-b partials -> the 3 scalar losses.
__global__ __launch_bounds__(64)
void ens_reduce1(const float* __restrict__ partial, double* __restrict__ ws2, int B)
{
    const int t  = threadIdx.x;     // 0..63
    const int i  = blockIdx.x;      // 0..63
    const int r0 = i * 128 + t * 2; // 128 rows per block
    double c = 0.0, f = 0.0, e = 0.0;
    #pragma unroll
    for (int k = 0; k < 2; ++k) {
        const int r = r0 + k;
        c += (double)partial[(size_t)r * 3 + 0];
        f += (double)partial[(size_t)r * 3 + 1];
        e += (double)partial[(size_t)r * 3 + 2];
    }
    #pragma unroll
    for (int off = 32; off; off >>= 1) {
        c += __shfl_xor(c, off);
        f += __shfl_xor(f, off);
        e += __shfl_xor(e, off);
    }
    if (t == 0) {
        ws2[(size_t)i * 3 + 0] = c;
        ws2[(size_t)i * 3 + 1] = f;
        ws2[(size_t)i * 3 + 2] = e;
    }
}

__global__ __launch_bounds__(64)
void ens_reduce2(const double* __restrict__ ws2, float* __restrict__ out, int B)
{
    const int t = threadIdx.x;
    double c = ws2[(size_t)t * 3 + 0];
    double f = ws2[(size_t)t * 3 + 1];
    double e = ws2[(size_t)t * 3 + 2];
    #pragma unroll
    for (int off = 32; off; off >>= 1) {
        c += __shfl_xor(c, off);
        f += __shfl_xor(f, off);
        e += __shfl_xor(e, off);
    }
    if (t == 0) {
        const size_t base = (size_t)B * CC;
        out[base + 0] = (float)(c / (double)((size_t)B * MM));  // child_loss
        out[base + 1] = (float)(f / (double)((size_t)B * MM));  // confidence_loss
        out[base + 2] = (float)(e / (double)B);                 // ensemble_loss
    }
}

extern "C" void kernel_launch(void* const* d_in, const int* in_sizes, int n_in,
                              void* d_out, int out_size, void* d_ws, size_t ws_size,
                              hipStream_t stream)
{
    const float* y      = (const float*)d_in[0];
    const int*   labels = (const int*)d_in[1];
    const int    B      = in_sizes[1];      // 8192
    float* out     = (float*)d_out;
    float* partial = (float*)d_ws;          // B*3 floats
    double* ws2    = (double*)((char*)d_ws + (((size_t)B * 3 * sizeof(float) + 255) & ~(size_t)255));

    ens_main<<<dim3(B), dim3(NT), 0, stream>>>(y, labels, out, partial, B);
    ens_reduce1<<<dim3(64), dim3(64), 0, stream>>>(partial, ws2, B);
    ens_reduce2<<<dim3(1), dim3(64), 0, stream>>>(ws2, out, B);
}

// Round 27
// 61.036 us; speedup vs baseline: 1.2115x; 1.0160x over previous
//
#include <hip/hip_runtime.h>
#include <math.h>

#define MM 16
#define CC 345
#define MC (MM*CC)     // 5520
#define MLDS 14        // rows staged in LDS; rows 14,15 read from global (L2)
#define MCL (MLDS*CC)  // 4830
#define KTOP 4
// Guard threshold in tc-space (validated R15/R20: absmax unchanged, ~0.5% trigger).
#define GAP_THR 3e-7f
#define NT 256         // 4 waves/block; ~19.8 KB LDS -> 8 blocks/CU

__device__ __forceinline__ float fexp(float x) { return __expf(x); }
__device__ __forceinline__ float flog(float x) { return __logf(x); }

// width-16 reductions over a 16-lane group
__device__ __forceinline__ float rmax16(float v) {
    #pragma unroll
    for (int off = 8; off; off >>= 1) v = fmaxf(v, __shfl_xor(v, off, 16));
    return v;
}
__device__ __forceinline__ float rmin16(float v) {
    #pragma unroll
    for (int off = 8; off; off >>= 1) v = fminf(v, __shfl_xor(v, off, 16));
    return v;
}
__device__ __forceinline__ float rsum16(float v) {
    #pragma unroll
    for (int off = 8; off; off >>= 1) v += __shfl_xor(v, off, 16);
    return v;
}

// One block per batch row b. 256 threads = 4 waves. 4 barriers (common path).
// Rows 0..13 staged in LDS; rows 14,15 served from global (first touch in
// phase 2, L2-hit re-read in phase 4). All numerics bit-identical to R24.
__global__ __launch_bounds__(NT)
void ens_main(const float* __restrict__ y, const int* __restrict__ labels,
              float* __restrict__ out, float* __restrict__ partial, int B)
{
    const int b   = blockIdx.x;
    const int tid = threadIdx.x;

    __shared__ float sl[MCL + 18];    // rows 0..13 (+pad for last float4)
    __shared__ float s_truep[MM], s_epl[MM], s_mx[MM], s_tpp[MM];
    __shared__ float s_w[MM], s_pw[MM];
    __shared__ float s_red[NT/64];
    __shared__ float s_lab;           // ems_out[label]
    __shared__ int   s_need;
    __shared__ unsigned s_selmask;

    const int label = labels[b];
    const float* yb = y + (size_t)b * MC;

    // ---- Phase 1: global -> LDS rows 0..13, vectorized float4.
    // 4830 floats -> 1208 float4 (last one spills 2 floats into pad; the
    // source is still in-bounds row-14 data, never read back from LDS).
    {
        const float4* src = reinterpret_cast<const float4*>(yb);
        float4* dst = reinterpret_cast<float4*>(sl);
        for (int i = tid; i < (MCL + 3) / 4; i += NT) dst[i] = src[i];
    }
    __syncthreads();   // #1

    // ---- Phase 2 (R24 pattern): per-m softmax stats, 16 lanes per m,
    // register-cached. Rows <14 from LDS, rows 14/15 from global (same
    // values -> bit-exact; m is uniform per 16-lane group).
    {
        const int m = tid >> 4;
        const int l = tid & 15;
        const float* row = (m < MLDS) ? (const float*)(sl + m * CC)
                                      : (yb + m * CC);
        float v[22];
        float mx = -INFINITY;
        #pragma unroll
        for (int k = 0; k < 22; ++k) {
            const int c = l + (k << 4);
            if (c < CC) { v[k] = row[c]; mx = fmaxf(mx, v[k]); }
            else          v[k] = 0.f;
        }
        mx = rmax16(mx);
        float se = 0.f;
        #pragma unroll
        for (int k = 0; k < 22; ++k) {
            const int c = l + (k << 4);
            if (c < CC) se += fexp(v[k] - mx);
        }
        se = rsum16(se);
        if (l == 0) {
            const float lt = row[label];
            s_mx[m]    = mx;                          // exact max, reused by 3b
            s_truep[m] = fexp(lt - mx) / se;          // fast probs[b,m,label]
            s_epl[m]   = -(lt - mx - flog(se));       // -log_softmax[b,m,label]
        }
    }
    __syncthreads();   // #2 — stats ready

    // ---- Phase 3a + speculative 3c (lanes 0..15, R24-verbatim): everything
    // except pw is sel-independent; pw published speculatively, corrected by
    // the rare guarded path.
    if (tid < MM) {
        const int l = tid;
        const size_t off_wm = (size_t)B * CC + 3;
        const size_t off_tc = off_wm + (size_t)B * MM;

        const float tp = s_truep[l];
        const float mx = rmax16(tp);
        const float e  = fexp(tp - mx);
        const float tc = e / rsum16(e);
        const float s1 = fmaxf(rsum16(fabsf(tc)), 1e-12f);
        const float wm = tc / s1;
        int rank = 0;
        #pragma unroll
        for (int j = 0; j < MM; ++j) {
            const float vj = __shfl(tc, j, 16);
            rank += (vj > tc) || (vj == tc && j < l);
        }
        const bool sel = (rank < KTOP);
        const float val4 = rmin16(sel ? tc : INFINITY);    // smallest selected
        const float val5 = rmax16(sel ? -INFINITY : tc);   // largest unselected
        if (l == 0) s_need = (val4 - val5 < GAP_THR) ? 1 : 0;

        // speculative pw from fast selection
        const float post = sel ? tc : 0.f;
        const float psum = fmaxf(rsum16(fabsf(post)), 1e-12f);
        s_pw[l] = post / psum;
        s_w[l]  = wm;

        // sel-independent finishers
        const float mw = rmax16(wm);
        const float ex = fexp(wm - mw);
        const float xv = ex / rsum16(ex);
        const float mt = rmax16(tc);
        const float et = fexp(tc - mt);
        const float tv = et / rsum16(et);
        const float childp = s_epl[l] * xv;
        const float confp  = fmaxf(xv, 0.f) - xv * tv + flog(1.f + fexp(-fabsf(xv)));
        const float childs = rsum16(childp);
        const float confs  = rsum16(confp);
        if (l == 0) {
            partial[(size_t)b * 3 + 0] = childs;
            partial[(size_t)b * 3 + 1] = confs;
        }
        out[off_wm + (size_t)b * MM + l] = xv;  // wm_soft
        out[off_tc + (size_t)b * MM + l] = tc;  // true_confs
    }
    __syncthreads();   // #3 — weights (speculative) + s_need ready

    // ---- Phase 3b (R24-verbatim internals, rare): BIT-EXACT round-1 chain;
    // corrects only s_pw. Rows <14 from LDS, 14/15 from global (same values).
    if (s_need) {
        {
            const int m = tid >> 4;
            const int l = tid & 15;
            const float* row = (m < MLDS) ? (const float*)(sl + m * CC)
                                          : (yb + m * CC);
            const float mx = s_mx[m];
            float se = 0.f;
            for (int c = l; c < CC; c += 16) se += expf(row[c] - mx);
            se = rsum16(se);
            if (l == 0) s_tpp[m] = expf(row[label] - mx) / se;
        }
        __syncthreads();
        if (tid == 0) {
            float tcp[MM];
            float mxx = -INFINITY;
            for (int m = 0; m < MM; ++m) mxx = fmaxf(mxx, s_tpp[m]);
            float ses = 0.f;
            for (int m = 0; m < MM; ++m) { tcp[m] = expf(s_tpp[m] - mxx); ses += tcp[m]; }
            for (int m = 0; m < MM; ++m) tcp[m] /= ses;
            bool used[MM];
            for (int m = 0; m < MM; ++m) used[m] = false;
            unsigned msk = 0;
            for (int k = 0; k < KTOP; ++k) {
                int bi = -1; float bv = -INFINITY;
                for (int m = 0; m < MM; ++m)
                    if (!used[m] && tcp[m] > bv) { bv = tcp[m]; bi = m; }
                used[bi] = true; msk |= (1u << bi);
            }
            s_selmask = msk;
        }
        __syncthreads();
        if (tid < MM) {
            const int l = tid;
            // recompute tc exactly as in 3a (same inputs -> same bits)
            const float tp = s_truep[l];
            const float mx = rmax16(tp);
            const float e  = fexp(tp - mx);
            const float tc = e / rsum16(e);
            const bool sel2 = ((s_selmask >> l) & 1u) != 0;
            const float post = sel2 ? tc : 0.f;
            const float psum = fmaxf(rsum16(fabsf(post)), 1e-12f);
            s_pw[l] = post / psum;
        }
        __syncthreads();   // republish corrected pw
    }

    // ---- Phase 4+5 fused (R24 pattern): two columns per thread (c, c+256);
    // rows <14 from LDS, rows 14/15 from global (L2-hot). Compile-time m ->
    // branch resolved at unroll, no divergence. Ensemble loss via UNSHIFTED
    // log-sum-exp; only ems[label] kept.
    {
        const int c0 = tid;            // always < 345
        const int c1 = tid + NT;
        const bool act1 = (c1 < CC);
        float a0 = 0.f, p0 = 0.f, a1 = 0.f, p1 = 0.f;
        #pragma unroll
        for (int m = 0; m < MM; ++m) {
            const float w_ = s_w[m];
            const float q_ = s_pw[m];
            float v0, v1 = 0.f;
            if (m < MLDS) {
                v0 = sl[m * CC + c0];
                if (act1) v1 = sl[m * CC + c1];
            } else {
                v0 = yb[m * CC + c0];
                if (act1) v1 = yb[m * CC + c1];
            }
            a0 = fmaf(v0, w_, a0);
            p0 = fmaf(v0, q_, p0);
            if (act1) {
                a1 = fmaf(v1, w_, a1);
                p1 = fmaf(v1, q_, p1);
            }
        }
        if (c0 == label) s_lab = a0;
        if (act1 && c1 == label) s_lab = a1;
        out[(size_t)b * CC + c0] = p0;             // ems_out_post
        if (act1) out[(size_t)b * CC + c1] = p1;

        float e = fexp(a0) + (act1 ? fexp(a1) : 0.f);
        #pragma unroll
        for (int off = 32; off; off >>= 1) e += __shfl_xor(e, off);
        if ((tid & 63) == 0) s_red[tid >> 6] = e;
        __syncthreads();   // #4 — covers s_lab + s_red
        if (tid == 0) {
            float s = 0.f;
            #pragma unroll
            for (int w = 0; w < NT/64; ++w) s += s_red[w];
            partial[(size_t)b * 3 + 2] = -(s_lab - flog(s));
        }
    }
}

// Two-stage deterministic reduction of per-b partials -> the 3 scalar losses.
__global__ __launch_bounds__(64)
void ens_reduce1(const float* __restrict__ partial, double* __restrict__ ws2, int B)
{
    const int t  = threadIdx.x;     // 0..63
    const int i  = blockIdx.x;      // 0..63
    const int r0 = i * 128 + t * 2; // 128 rows per block
    double c = 0.0, f = 0.0, e = 0.0;
    #pragma unroll
    for (int k = 0; k < 2; ++k) {
        const int r = r0 + k;
        c += (double)partial[(size_t)r * 3 + 0];
        f += (double)partial[(size_t)r * 3 + 1];
        e += (double)partial[(size_t)r * 3 + 2];
    }
    #pragma unroll
    for (int off = 32; off; off >>= 1) {
        c += __shfl_xor(c, off);
        f += __shfl_xor(f, off);
        e += __shfl_xor(e, off);
    }
    if (t == 0) {
        ws2[(size_t)i * 3 + 0] = c;
        ws2[(size_t)i * 3 + 1] = f;
        ws2[(size_t)i * 3 + 2] = e;
    }
}

__global__ __launch_bounds__(64)
void ens_reduce2(const double* __restrict__ ws2, float* __restrict__ out, int B)
{
    const int t = threadIdx.x;
    double c = ws2[(size_t)t * 3 + 0];
    double f = ws2[(size_t)t * 3 + 1];
    double e = ws2[(size_t)t * 3 + 2];
    #pragma unroll
    for (int off = 32; off; off >>= 1) {
        c += __shfl_xor(c, off);
        f += __shfl_xor(f, off);
        e += __shfl_xor(e, off);
    }
    if (t == 0) {
        const size_t base = (size_t)B * CC;
        out[base + 0] = (float)(c / (double)((size_t)B * MM));  // child_loss
        out[base + 1] = (float)(f / (double)((size_t)B * MM));  // confidence_loss
        out[base + 2] = (float)(e / (double)B);                 // ensemble_loss
    }
}

extern "C" void kernel_launch(void* const* d_in, const int* in_sizes, int n_in,
                              void* d_out, int out_size, void* d_ws, size_t ws_size,
                              hipStream_t stream)
{
    const float* y      = (const float*)d_in[0];
    const int*   labels = (const int*)d_in[1];
    const int    B      = in_sizes[1];      // 8192
    float* out     = (float*)d_out;
    float* partial = (float*)d_ws;          // B*3 floats
    double* ws2    = (double*)((char*)d_ws + (((size_t)B * 3 * sizeof(float) + 255) & ~(size_t)255));

    ens_main<<<dim3(B), dim3(NT), 0, stream>>>(y, labels, out, partial, B);
    ens_reduce1<<<dim3(64), dim3(64), 0, stream>>>(partial, ws2, B);
    ens_reduce2<<<dim3(1), dim3(64), 0, stream>>>(ws2, out, B);
}

// Round 28
// 55.873 us; speedup vs baseline: 1.3235x; 1.0924x over previous
//
#include <hip/hip_runtime.h>
#include <math.h>

#define MM 16
#define CC 345
#define MC (MM*CC)   // 5520
#define KTOP 4
// Guard threshold in tc-space (validated R15/R20: absmax unchanged, ~0.5% trigger).
#define GAP_THR 3e-7f
#define NT 256       // 4 waves/block; ~22.3 KB LDS -> 7 blocks/CU

__device__ __forceinline__ float fexp(float x) { return __expf(x); }
__device__ __forceinline__ float flog(float x) { return __logf(x); }

// width-16 reductions over a 16-lane group
__device__ __forceinline__ float rmax16(float v) {
    #pragma unroll
    for (int off = 8; off; off >>= 1) v = fmaxf(v, __shfl_xor(v, off, 16));
    return v;
}
__device__ __forceinline__ float rmin16(float v) {
    #pragma unroll
    for (int off = 8; off; off >>= 1) v = fminf(v, __shfl_xor(v, off, 16));
    return v;
}
__device__ __forceinline__ float rsum16(float v) {
    #pragma unroll
    for (int off = 8; off; off >>= 1) v += __shfl_xor(v, off, 16);
    return v;
}

// One block per batch row b. 256 threads = 4 waves. 3 barriers (common path).
// Wave w stages ONLY its quarter of the tile (rows 4w..4w+3 = floats
// [w*1380,(w+1)*1380), float4-aligned) and then reads those same rows for
// stats WITHOUT a barrier: DS ops from one wave complete in order, and
// phase 2's mapping (m = tid>>4) touches exactly the wave's own rows.
// First barrier then publishes stats + the full tile for phases 3b/4.
__global__ __launch_bounds__(NT)
void ens_main(const float* __restrict__ y, const int* __restrict__ labels,
              float* __restrict__ out, float* __restrict__ partial, int B)
{
    const int b   = blockIdx.x;
    const int tid = threadIdx.x;

    __shared__ float sl[MC + 64];     // logits tile (+pad) ~22.3 KB
    __shared__ float s_truep[MM], s_epl[MM], s_mx[MM], s_tpp[MM];
    __shared__ float s_w[MM], s_pw[MM];
    __shared__ float s_red[NT/64];
    __shared__ float s_lab;           // ems_out[label]
    __shared__ int   s_need;
    __shared__ unsigned s_selmask;

    const int label = labels[b];
    const float* yb = y + (size_t)b * MC;

    // ---- Phase 1+2 fused (no barrier between): wave-local staging + stats.
    {
        const int w  = tid >> 6;      // wave 0..3
        const int lw = tid & 63;
        // stage this wave's quarter: 345 float4 (rows 4w..4w+3)
        const float4* src = reinterpret_cast<const float4*>(yb) + w * 345;
        float4* dst = reinterpret_cast<float4*>(sl) + w * 345;
        for (int i = lw; i < 345; i += 64) dst[i] = src[i];

        // stats (R24-verbatim pattern): 16 lanes per m; m = 4w + (lane>>4)
        // -> reads only this wave's just-written rows (in-order DS).
        const int m = tid >> 4;
        const int l = tid & 15;
        const float* row = sl + m * CC;
        float v[22];
        float mx = -INFINITY;
        #pragma unroll
        for (int k = 0; k < 22; ++k) {
            const int c = l + (k << 4);
            if (c < CC) { v[k] = row[c]; mx = fmaxf(mx, v[k]); }
            else          v[k] = 0.f;
        }
        mx = rmax16(mx);
        float se = 0.f;
        #pragma unroll
        for (int k = 0; k < 22; ++k) {
            const int c = l + (k << 4);
            if (c < CC) se += fexp(v[k] - mx);
        }
        se = rsum16(se);
        if (l == 0) {
            const float lt = row[label];
            s_mx[m]    = mx;                          // exact max, reused by 3b
            s_truep[m] = fexp(lt - mx) / se;          // fast probs[b,m,label]
            s_epl[m]   = -(lt - mx - flog(se));       // -log_softmax[b,m,label]
        }
    }
    __syncthreads();   // #1 — stats + full tile ready

    // ---- Phase 3a + speculative 3c (lanes 0..15, R24-verbatim): everything
    // except pw is sel-independent; pw published speculatively, corrected by
    // the rare guarded path.
    if (tid < MM) {
        const int l = tid;
        const size_t off_wm = (size_t)B * CC + 3;
        const size_t off_tc = off_wm + (size_t)B * MM;

        const float tp = s_truep[l];
        const float mx = rmax16(tp);
        const float e  = fexp(tp - mx);
        const float tc = e / rsum16(e);
        const float s1 = fmaxf(rsum16(fabsf(tc)), 1e-12f);
        const float wm = tc / s1;
        int rank = 0;
        #pragma unroll
        for (int j = 0; j < MM; ++j) {
            const float vj = __shfl(tc, j, 16);
            rank += (vj > tc) || (vj == tc && j < l);
        }
        const bool sel = (rank < KTOP);
        const float val4 = rmin16(sel ? tc : INFINITY);    // smallest selected
        const float val5 = rmax16(sel ? -INFINITY : tc);   // largest unselected
        if (l == 0) s_need = (val4 - val5 < GAP_THR) ? 1 : 0;

        // speculative pw from fast selection
        const float post = sel ? tc : 0.f;
        const float psum = fmaxf(rsum16(fabsf(post)), 1e-12f);
        s_pw[l] = post / psum;
        s_w[l]  = wm;

        // sel-independent finishers
        const float mw = rmax16(wm);
        const float ex = fexp(wm - mw);
        const float xv = ex / rsum16(ex);
        const float mt = rmax16(tc);
        const float et = fexp(tc - mt);
        const float tv = et / rsum16(et);
        const float childp = s_epl[l] * xv;
        const float confp  = fmaxf(xv, 0.f) - xv * tv + flog(1.f + fexp(-fabsf(xv)));
        const float childs = rsum16(childp);
        const float confs  = rsum16(confp);
        if (l == 0) {
            partial[(size_t)b * 3 + 0] = childs;
            partial[(size_t)b * 3 + 1] = confs;
        }
        out[off_wm + (size_t)b * MM + l] = xv;  // wm_soft
        out[off_tc + (size_t)b * MM + l] = tc;  // true_confs
    }
    __syncthreads();   // #2 — weights (speculative) + s_need ready

    // ---- Phase 3b (R24-verbatim internals, rare): BIT-EXACT round-1 chain;
    // corrects only s_pw. Block-uniform condition -> conditional barriers legal.
    if (s_need) {
        {
            const int m = tid >> 4;
            const int l = tid & 15;
            const float* row = sl + m * CC;
            const float mx = s_mx[m];
            float se = 0.f;
            for (int c = l; c < CC; c += 16) se += expf(row[c] - mx);
            se = rsum16(se);
            if (l == 0) s_tpp[m] = expf(row[label] - mx) / se;
        }
        __syncthreads();
        if (tid == 0) {
            float tcp[MM];
            float mxx = -INFINITY;
            for (int m = 0; m < MM; ++m) mxx = fmaxf(mxx, s_tpp[m]);
            float ses = 0.f;
            for (int m = 0; m < MM; ++m) { tcp[m] = expf(s_tpp[m] - mxx); ses += tcp[m]; }
            for (int m = 0; m < MM; ++m) tcp[m] /= ses;
            bool used[MM];
            for (int m = 0; m < MM; ++m) used[m] = false;
            unsigned msk = 0;
            for (int k = 0; k < KTOP; ++k) {
                int bi = -1; float bv = -INFINITY;
                for (int m = 0; m < MM; ++m)
                    if (!used[m] && tcp[m] > bv) { bv = tcp[m]; bi = m; }
                used[bi] = true; msk |= (1u << bi);
            }
            s_selmask = msk;
        }
        __syncthreads();
        if (tid < MM) {
            const int l = tid;
            // recompute tc exactly as in 3a (same inputs -> same bits)
            const float tp = s_truep[l];
            const float mx = rmax16(tp);
            const float e  = fexp(tp - mx);
            const float tc = e / rsum16(e);
            const bool sel2 = ((s_selmask >> l) & 1u) != 0;
            const float post = sel2 ? tc : 0.f;
            const float psum = fmaxf(rsum16(fabsf(post)), 1e-12f);
            s_pw[l] = post / psum;
        }
        __syncthreads();   // republish corrected pw
    }

    // ---- Phase 4+5 fused (R24-verbatim): two columns per thread (c, c+256)
    // from the LDS tile; ensemble loss via UNSHIFTED log-sum-exp; only
    // ems[label] kept (single s_lab float).
    {
        const int c0 = tid;            // always < 345
        const int c1 = tid + NT;
        const bool act1 = (c1 < CC);
        float a0 = 0.f, p0 = 0.f, a1 = 0.f, p1 = 0.f;
        #pragma unroll
        for (int m = 0; m < MM; ++m) {
            const float w_ = s_w[m];
            const float q_ = s_pw[m];
            const float v0 = sl[m * CC + c0];
            a0 = fmaf(v0, w_, a0);
            p0 = fmaf(v0, q_, p0);
            if (act1) {
                const float v1 = sl[m * CC + c1];
                a1 = fmaf(v1, w_, a1);
                p1 = fmaf(v1, q_, p1);
            }
        }
        if (c0 == label) s_lab = a0;
        if (act1 && c1 == label) s_lab = a1;
        out[(size_t)b * CC + c0] = p0;             // ems_out_post
        if (act1) out[(size_t)b * CC + c1] = p1;

        float e = fexp(a0) + (act1 ? fexp(a1) : 0.f);
        #pragma unroll
        for (int off = 32; off; off >>= 1) e += __shfl_xor(e, off);
        if ((tid & 63) == 0) s_red[tid >> 6] = e;
        __syncthreads();   // #3 — covers s_lab + s_red
        if (tid == 0) {
            float s = 0.f;
            #pragma unroll
            for (int w = 0; w < NT/64; ++w) s += s_red[w];
            partial[(size_t)b * 3 + 2] = -(s_lab - flog(s));
        }
    }
}

// Two-stage deterministic reduction of per-b partials -> the 3 scalar losses.
__global__ __launch_bounds__(64)
void ens_reduce1(const float* __restrict__ partial, double* __restrict__ ws2, int B)
{
    const int t  = threadIdx.x;     // 0..63
    const int i  = blockIdx.x;      // 0..63
    const int r0 = i * 128 + t * 2; // 128 rows per block
    double c = 0.0, f = 0.0, e = 0.0;
    #pragma unroll
    for (int k = 0; k < 2; ++k) {
        const int r = r0 + k;
        c += (double)partial[(size_t)r * 3 + 0];
        f += (double)partial[(size_t)r * 3 + 1];
        e += (double)partial[(size_t)r * 3 + 2];
    }
    #pragma unroll
    for (int off = 32; off; off >>= 1) {
        c += __shfl_xor(c, off);
        f += __shfl_xor(f, off);
        e += __shfl_xor(e, off);
    }
    if (t == 0) {
        ws2[(size_t)i * 3 + 0] = c;
        ws2[(size_t)i * 3 + 1] = f;
        ws2[(size_t)i * 3 + 2] = e;
    }
}

__global__ __launch_bounds__(64)
void ens_reduce2(const double* __restrict__ ws2, float* __restrict__ out, int B)
{
    const int t = threadIdx.x;
    double c = ws2[(size_t)t * 3 + 0];
    double f = ws2[(size_t)t * 3 + 1];
    double e = ws2[(size_t)t * 3 + 2];
    #pragma unroll
    for (int off = 32; off; off >>= 1) {
        c += __shfl_xor(c, off);
        f += __shfl_xor(f, off);
        e += __shfl_xor(e, off);
    }
    if (t == 0) {
        const size_t base = (size_t)B * CC;
        out[base + 0] = (float)(c / (double)((size_t)B * MM));  // child_loss
        out[base + 1] = (float)(f / (double)((size_t)B * MM));  // confidence_loss
        out[base + 2] = (float)(e / (double)B);                 // ensemble_loss
    }
}

extern "C" void kernel_launch(void* const* d_in, const int* in_sizes, int n_in,
                              void* d_out, int out_size, void* d_ws, size_t ws_size,
                              hipStream_t stream)
{
    const float* y      = (const float*)d_in[0];
    const int*   labels = (const int*)d_in[1];
    const int    B      = in_sizes[1];      // 8192
    float* out     = (float*)d_out;
    float* partial = (float*)d_ws;          // B*3 floats
    double* ws2    = (double*)((char*)d_ws + (((size_t)B * 3 * sizeof(float) + 255) & ~(size_t)255));

    ens_main<<<dim3(B), dim3(NT), 0, stream>>>(y, labels, out, partial, B);
    ens_reduce1<<<dim3(64), dim3(64), 0, stream>>>(partial, ws2, B);
    ens_reduce2<<<dim3(1), dim3(64), 0, stream>>>(ws2, out, B);
}